// Round 14
// baseline (992.001 us; speedup 1.0000x reference)
//
#include <hip/hip_runtime.h>

#define S 1024
#define D 64
#define R 16            // rows per block
#define BH 64           // B*H
#define SUBP 68         // per-wave sub-chunk stride (64 + 4 pad)

typedef float v4f __attribute__((ext_vector_type(4)));

__global__ __launch_bounds__(256, 4)   // proven R7 config: VGPR=64, no spill, deterministic
void attn_fused_kernel(const float* __restrict__ q,
                       const float* __restrict__ k,      // [BH][D][S] (pre-transposed)
                       const float* __restrict__ v,      // [BH][S][D]
                       const float* __restrict__ prev,   // [BH][S][S]
                       const float* __restrict__ mask,   // [S][S]
                       const float* __restrict__ scale_p,
                       float* __restrict__ out,          // [BH][S][D]
                       float* __restrict__ weights,      // [BH][S][S]
                       float* __restrict__ scores)       // [BH][S][S]
{
    __shared__ float q_lds[R][D];             // 4 KB
    __shared__ float s_sub[4][R][SUBP];       // 17 KB: W sub-chunk, reused for out partials
    __shared__ float red_sum[4][R];

    // XCD-bijective swizzle: XCD x serves bh in [8x, 8x+8) -> K/V stay L2-resident
    const int bid  = (int)blockIdx.x;           // 0..4095
    const int wg   = (bid & 7) * 512 + (bid >> 3);
    const int tile = wg & 63;                   // 0..63
    const int bh   = wg >> 6;                   // 0..63

    const int tid  = (int)threadIdx.x;
    const int lane = tid & 63;
    const int wid  = tid >> 6;
    const int r0   = tile * R;

    const float* qb = q    + (size_t)bh * S * D + (size_t)r0 * D;
    const float* kb = k    + (size_t)bh * D * S;
    const float* vb = v    + (size_t)bh * S * D;
    const float* pb = prev + (size_t)bh * S * S + (size_t)r0 * S;
    const float* mb = mask + (size_t)r0 * S;
    float* wout = weights + (size_t)bh * S * S + (size_t)r0 * S;
    float* sout = scores  + (size_t)bh * S * S + (size_t)r0 * S;
    float* oout = out     + (size_t)bh * S * D + (size_t)r0 * D;

    const float scale  = *scale_p;        // exactly 0.125
    const float rscale = 1.0f / scale;    // exactly 8.0 -> seeding is rounding-free

    // ---- load q tile (16x64 = 1024 floats) via one float4 per thread ----
    {
        float4 qv = *(const float4*)(qb + (size_t)tid * 4);
        *(float4*)&q_lds[tid >> 4][(tid & 15) * 4] = qv;
    }
    __syncthreads();

    const int t0 = tid * 4;
    float acc[R][4];

    // ---- seed acc = (prev + mask) * (1/scale); prev is read-once stream ----
#pragma unroll
    for (int r = 0; r < R; ++r) {
        v4f p4 = __builtin_nontemporal_load((const v4f*)(pb + (size_t)r * S + t0));
        v4f m4 = *(const v4f*)(mb + (size_t)r * S + t0);
        acc[r][0] = (p4[0] + m4[0]) * rscale;
        acc[r][1] = (p4[1] + m4[1]) * rscale;
        acc[r][2] = (p4[2] + m4[2]) * rscale;
        acc[r][3] = (p4[3] + m4[3]) * rscale;
    }

    // ---- phase 1: QK^T accumulates on top of the seed (K is L2-hot) ----
#pragma unroll 2
    for (int kk = 0; kk < D / 4; ++kk) {
        const float* kp = kb + (size_t)(kk * 4) * S + t0;
        float4 k0 = *(const float4*)(kp);
        float4 k1 = *(const float4*)(kp + S);
        float4 k2 = *(const float4*)(kp + 2 * S);
        float4 k3 = *(const float4*)(kp + 3 * S);
#pragma unroll
        for (int r = 0; r < R; ++r) {
            float4 q4 = *(const float4*)&q_lds[r][kk * 4];
            acc[r][0] = fmaf(q4.w, k3.x, fmaf(q4.z, k2.x, fmaf(q4.y, k1.x, fmaf(q4.x, k0.x, acc[r][0]))));
            acc[r][1] = fmaf(q4.w, k3.y, fmaf(q4.z, k2.y, fmaf(q4.y, k1.y, fmaf(q4.x, k0.y, acc[r][1]))));
            acc[r][2] = fmaf(q4.w, k3.z, fmaf(q4.z, k2.z, fmaf(q4.y, k1.z, fmaf(q4.x, k0.z, acc[r][2]))));
            acc[r][3] = fmaf(q4.w, k3.w, fmaf(q4.z, k2.w, fmaf(q4.y, k1.w, fmaf(q4.x, k0.w, acc[r][3]))));
        }
    }

    // ---- acc = scores (scaled); NO store yet (keeps the softmax barrier drain-free) ----
#pragma unroll
    for (int r = 0; r < R; ++r) {
        acc[r][0] *= scale; acc[r][1] *= scale; acc[r][2] *= scale; acc[r][3] *= scale;
    }

    // ---- pass 1: row sums of exp(scores); exp values discarded ----
    {
#pragma unroll
        for (int r = 0; r < R; ++r) {
            float e0 = __expf(acc[r][0]);
            float e1 = __expf(acc[r][1]);
            float e2 = __expf(acc[r][2]);
            float e3 = __expf(acc[r][3]);
            float ssum = (e0 + e1) + (e2 + e3);
#pragma unroll
            for (int off = 32; off > 0; off >>= 1)
                ssum += __shfl_xor(ssum, off);
            if (lane == 0) red_sum[wid][r] = ssum;
        }
    }
    __syncthreads();   // drain-free barrier: no outstanding global stores here

    // ---- kill exp-CSE across the barrier (else compiler keeps 64 exp results -> spill) ----
#pragma unroll
    for (int r = 0; r < R; ++r) {
        asm volatile("" : "+v"(acc[r][0]), "+v"(acc[r][1]), "+v"(acc[r][2]), "+v"(acc[r][3]));
    }

    // ---- pass 2: store scores, recompute w = exp(s)*inv, store weights ----
    // these nt stores drain under phase-3 compute, not at a barrier
#pragma unroll
    for (int r = 0; r < R; ++r) {
        float gs = (red_sum[0][r] + red_sum[1][r]) + (red_sum[2][r] + red_sum[3][r]);
        float inv = 1.0f / gs;
        v4f s4v = { acc[r][0], acc[r][1], acc[r][2], acc[r][3] };
        __builtin_nontemporal_store(s4v, (v4f*)(sout + (size_t)r * S + t0));
        acc[r][0] = __expf(acc[r][0]) * inv;
        acc[r][1] = __expf(acc[r][1]) * inv;
        acc[r][2] = __expf(acc[r][2]) * inv;
        acc[r][3] = __expf(acc[r][3]) * inv;
        v4f w4v = { acc[r][0], acc[r][1], acc[r][2], acc[r][3] };
        __builtin_nontemporal_store(w4v, (v4f*)(wout + (size_t)r * S + t0));
    }

    // ---- phase 3 (split-t): wave w handles t in [256w, 256w+256) ----
    const int g0 = lane >> 4;          // sub-range owner / row-group
    const int dq = lane & 15;          // d-quad
    const float* vw = vb + (size_t)(wid * 256) * D;

    float4 p0 = {0.f,0.f,0.f,0.f};
    float4 p1 = {0.f,0.f,0.f,0.f};
    float4 p2 = {0.f,0.f,0.f,0.f};
    float4 p3 = {0.f,0.f,0.f,0.f};

#pragma unroll 1
    for (int s4 = 0; s4 < 4; ++s4) {
        asm volatile("" ::: "memory");
        if (g0 == s4) {
#pragma unroll
            for (int r = 0; r < R; ++r) {
                float4 w4 = { acc[r][0], acc[r][1], acc[r][2], acc[r][3] };
                *(float4*)&s_sub[wid][r][dq * 4] = w4;
            }
        }
        asm volatile("s_waitcnt lgkmcnt(0)" ::: "memory");

        const float* vs = vw + (size_t)(s4 * 64) * D;
#pragma unroll 2
        for (int j = 0; j < 16; ++j) {
            float4 w0 = *(const float4*)&s_sub[wid][g0     ][j * 4];
            float4 w1 = *(const float4*)&s_sub[wid][g0 + 4 ][j * 4];
            float4 w2 = *(const float4*)&s_sub[wid][g0 + 8 ][j * 4];
            float4 w3 = *(const float4*)&s_sub[wid][g0 + 12][j * 4];
            const float* vp = vs + (size_t)(j * 4) * D + dq * 4;
            float4 v0 = *(const float4*)(vp);
            float4 v1 = *(const float4*)(vp + D);
            float4 v2 = *(const float4*)(vp + 2 * D);
            float4 v3 = *(const float4*)(vp + 3 * D);
            p0.x = fmaf(w0.w, v3.x, fmaf(w0.z, v2.x, fmaf(w0.y, v1.x, fmaf(w0.x, v0.x, p0.x))));
            p0.y = fmaf(w0.w, v3.y, fmaf(w0.z, v2.y, fmaf(w0.y, v1.y, fmaf(w0.x, v0.y, p0.y))));
            p0.z = fmaf(w0.w, v3.z, fmaf(w0.z, v2.z, fmaf(w0.y, v1.z, fmaf(w0.x, v0.z, p0.z))));
            p0.w = fmaf(w0.w, v3.w, fmaf(w0.z, v2.w, fmaf(w0.y, v1.w, fmaf(w0.x, v0.w, p0.w))));
            p1.x = fmaf(w1.w, v3.x, fmaf(w1.z, v2.x, fmaf(w1.y, v1.x, fmaf(w1.x, v0.x, p1.x))));
            p1.y = fmaf(w1.w, v3.y, fmaf(w1.z, v2.y, fmaf(w1.y, v1.y, fmaf(w1.x, v0.y, p1.y))));
            p1.z = fmaf(w1.w, v3.z, fmaf(w1.z, v2.z, fmaf(w1.y, v1.z, fmaf(w1.x, v0.z, p1.z))));
            p1.w = fmaf(w1.w, v3.w, fmaf(w1.z, v2.w, fmaf(w1.y, v1.w, fmaf(w1.x, v0.w, p1.w))));
            p2.x = fmaf(w2.w, v3.x, fmaf(w2.z, v2.x, fmaf(w2.y, v1.x, fmaf(w2.x, v0.x, p2.x))));
            p2.y = fmaf(w2.w, v3.y, fmaf(w2.z, v2.y, fmaf(w2.y, v1.y, fmaf(w2.x, v0.y, p2.y))));
            p2.z = fmaf(w2.w, v3.z, fmaf(w2.z, v2.z, fmaf(w2.y, v1.z, fmaf(w2.x, v0.z, p2.z))));
            p2.w = fmaf(w2.w, v3.w, fmaf(w2.z, v2.w, fmaf(w2.y, v1.w, fmaf(w2.x, v0.w, p2.w))));
            p3.x = fmaf(w3.w, v3.x, fmaf(w3.z, v2.x, fmaf(w3.y, v1.x, fmaf(w3.x, v0.x, p3.x))));
            p3.y = fmaf(w3.w, v3.y, fmaf(w3.z, v2.y, fmaf(w3.y, v1.y, fmaf(w3.x, v0.y, p3.y))));
            p3.z = fmaf(w3.w, v3.z, fmaf(w3.z, v2.z, fmaf(w3.y, v1.z, fmaf(w3.x, v0.z, p3.z))));
            p3.w = fmaf(w3.w, v3.w, fmaf(w3.z, v2.w, fmaf(w3.y, v1.w, fmaf(w3.x, v0.w, p3.w))));
        }
    }

    // ---- out partials into the SAME per-wave region (own last read done) ----
    asm volatile("" ::: "memory");
    *(float4*)&s_sub[wid][g0     ][dq * 4] = p0;
    *(float4*)&s_sub[wid][g0 + 4 ][dq * 4] = p1;
    *(float4*)&s_sub[wid][g0 + 8 ][dq * 4] = p2;
    *(float4*)&s_sub[wid][g0 + 12][dq * 4] = p3;
    __syncthreads();
    {
        const int row = tid >> 4;      // 0..15
        const int dq2 = tid & 15;      // 0..15
        float4 a0 = *(const float4*)&s_sub[0][row][dq2 * 4];
        float4 a1 = *(const float4*)&s_sub[1][row][dq2 * 4];
        float4 a2 = *(const float4*)&s_sub[2][row][dq2 * 4];
        float4 a3 = *(const float4*)&s_sub[3][row][dq2 * 4];
        v4f o;
        o[0] = (a0.x + a1.x) + (a2.x + a3.x);
        o[1] = (a0.y + a1.y) + (a2.y + a3.y);
        o[2] = (a0.z + a1.z) + (a2.z + a3.z);
        o[3] = (a0.w + a1.w) + (a2.w + a3.w);
        __builtin_nontemporal_store(o, (v4f*)(oout + (size_t)row * D + dq2 * 4));
    }
}

extern "C" void kernel_launch(void* const* d_in, const int* in_sizes, int n_in,
                              void* d_out, int out_size, void* d_ws, size_t ws_size,
                              hipStream_t stream) {
    (void)in_sizes; (void)n_in; (void)out_size; (void)d_ws; (void)ws_size;
    const float* q     = (const float*)d_in[0];
    const float* k     = (const float*)d_in[1];
    const float* v     = (const float*)d_in[2];
    const float* prev  = (const float*)d_in[3];
    const float* mask  = (const float*)d_in[4];
    const float* scale = (const float*)d_in[5];

    float* out     = (float*)d_out;                       // 4*16*1024*64   = 4194304
    float* weights = out + (size_t)4 * 16 * 1024 * 64;    // 4*16*1024*1024 = 67108864
    float* scores  = weights + (size_t)4 * 16 * 1024 * 1024;

    attn_fused_kernel<<<dim3(4096), 256, 0, stream>>>(q, k, v, prev, mask, scale,
                                                      out, weights, scores);
}

// Round 15
// 392.475 us; speedup vs baseline: 2.5275x; 2.5275x over previous
//
#include <hip/hip_runtime.h>

#define S 1024
#define D 64
#define R 16            // rows per block
#define BH 64           // B*H
#define SUBP 68         // per-wave sub-chunk stride (64 + 4 pad)

typedef float v4f __attribute__((ext_vector_type(4)));

// ================= Kernel A: scores + softmax + weights (R7 minus PV) =================
__global__ __launch_bounds__(256, 4)
void attn_scores_kernel(const float* __restrict__ q,
                        const float* __restrict__ k,      // [BH][D][S]
                        const float* __restrict__ prev,   // [BH][S][S]
                        const float* __restrict__ mask,   // [S][S]
                        const float* __restrict__ scale_p,
                        float* __restrict__ weights,      // [BH][S][S]
                        float* __restrict__ scores)       // [BH][S][S]
{
    __shared__ float q_lds[R][D];
    __shared__ float red_sum[4][R];

    const int bid  = (int)blockIdx.x;           // 0..4095
    const int wg   = (bid & 7) * 512 + (bid >> 3);
    const int tile = wg & 63;
    const int bh   = wg >> 6;

    const int tid  = (int)threadIdx.x;
    const int lane = tid & 63;
    const int wid  = tid >> 6;
    const int r0   = tile * R;

    const float* qb = q    + (size_t)bh * S * D + (size_t)r0 * D;
    const float* kb = k    + (size_t)bh * D * S;
    const float* pb = prev + (size_t)bh * S * S + (size_t)r0 * S;
    const float* mb = mask + (size_t)r0 * S;
    float* wout = weights + (size_t)bh * S * S + (size_t)r0 * S;
    float* sout = scores  + (size_t)bh * S * S + (size_t)r0 * S;

    const float scale  = *scale_p;        // exactly 0.125
    const float rscale = 1.0f / scale;    // exactly 8.0

    {
        float4 qv = *(const float4*)(qb + (size_t)tid * 4);
        *(float4*)&q_lds[tid >> 4][(tid & 15) * 4] = qv;
    }
    __syncthreads();

    const int t0 = tid * 4;
    float acc[R][4];

#pragma unroll
    for (int r = 0; r < R; ++r) {
        v4f p4 = __builtin_nontemporal_load((const v4f*)(pb + (size_t)r * S + t0));
        v4f m4 = *(const v4f*)(mb + (size_t)r * S + t0);
        acc[r][0] = (p4[0] + m4[0]) * rscale;
        acc[r][1] = (p4[1] + m4[1]) * rscale;
        acc[r][2] = (p4[2] + m4[2]) * rscale;
        acc[r][3] = (p4[3] + m4[3]) * rscale;
    }

#pragma unroll 2
    for (int kk = 0; kk < D / 4; ++kk) {
        const float* kp = kb + (size_t)(kk * 4) * S + t0;
        float4 k0 = *(const float4*)(kp);
        float4 k1 = *(const float4*)(kp + S);
        float4 k2 = *(const float4*)(kp + 2 * S);
        float4 k3 = *(const float4*)(kp + 3 * S);
#pragma unroll
        for (int r = 0; r < R; ++r) {
            float4 q4 = *(const float4*)&q_lds[r][kk * 4];
            acc[r][0] = fmaf(q4.w, k3.x, fmaf(q4.z, k2.x, fmaf(q4.y, k1.x, fmaf(q4.x, k0.x, acc[r][0]))));
            acc[r][1] = fmaf(q4.w, k3.y, fmaf(q4.z, k2.y, fmaf(q4.y, k1.y, fmaf(q4.x, k0.y, acc[r][1]))));
            acc[r][2] = fmaf(q4.w, k3.z, fmaf(q4.z, k2.z, fmaf(q4.y, k1.z, fmaf(q4.x, k0.z, acc[r][2]))));
            acc[r][3] = fmaf(q4.w, k3.w, fmaf(q4.z, k2.w, fmaf(q4.y, k1.w, fmaf(q4.x, k0.w, acc[r][3]))));
        }
    }

#pragma unroll
    for (int r = 0; r < R; ++r) {
        acc[r][0] *= scale; acc[r][1] *= scale; acc[r][2] *= scale; acc[r][3] *= scale;
        v4f s4v = { acc[r][0], acc[r][1], acc[r][2], acc[r][3] };
        __builtin_nontemporal_store(s4v, (v4f*)(sout + (size_t)r * S + t0));
    }

    {
#pragma unroll
        for (int r = 0; r < R; ++r) {
            acc[r][0] = __expf(acc[r][0]);
            acc[r][1] = __expf(acc[r][1]);
            acc[r][2] = __expf(acc[r][2]);
            acc[r][3] = __expf(acc[r][3]);
            float ssum = (acc[r][0] + acc[r][1]) + (acc[r][2] + acc[r][3]);
#pragma unroll
            for (int off = 32; off > 0; off >>= 1)
                ssum += __shfl_xor(ssum, off);
            if (lane == 0) red_sum[wid][r] = ssum;
        }
    }
    __syncthreads();

#pragma unroll
    for (int r = 0; r < R; ++r) {
        float gs = (red_sum[0][r] + red_sum[1][r]) + (red_sum[2][r] + red_sum[3][r]);
        float inv = 1.0f / gs;
        v4f w4v = { acc[r][0] * inv, acc[r][1] * inv, acc[r][2] * inv, acc[r][3] * inv };
        __builtin_nontemporal_store(w4v, (v4f*)(wout + (size_t)r * S + t0));
    }
}

// ================= Kernel B: out = W @ V (streaming, high occupancy) =================
__global__ __launch_bounds__(256, 6)   // VGPR cap ~42; kernel sized to fit -> 6 blocks/CU
void attn_pv_kernel(const float* __restrict__ weights,   // [BH][S][S]
                    const float* __restrict__ v,         // [BH][S][D]
                    float* __restrict__ out)             // [BH][S][D]
{
    __shared__ float s_sub[4][R][SUBP];       // 17.4 KB: W sub-chunk, reused for out partials

    const int bid  = (int)blockIdx.x;
    const int wg   = (bid & 7) * 512 + (bid >> 3);
    const int tile = wg & 63;
    const int bh   = wg >> 6;

    const int tid  = (int)threadIdx.x;
    const int lane = tid & 63;
    const int wid  = tid >> 6;
    const int r0   = tile * R;

    const float* wb = weights + (size_t)bh * S * S + (size_t)r0 * S + wid * 256;
    const float* vw = v + (size_t)bh * S * D + (size_t)(wid * 256) * D;
    float* oout = out + (size_t)bh * S * D + (size_t)r0 * D;

    const int g0 = lane >> 4;          // row-group
    const int dq = lane & 15;          // quad index

    float4 p0 = {0.f,0.f,0.f,0.f};
    float4 p1 = {0.f,0.f,0.f,0.f};
    float4 p2 = {0.f,0.f,0.f,0.f};
    float4 p3 = {0.f,0.f,0.f,0.f};

#pragma unroll 1
    for (int s4 = 0; s4 < 4; ++s4) {
        // cooperative (wave-private) load of W[16 rows][64-col sub-window] from global
        // lane (g,c): rows 4*rr+g, cols 64*s4 + c*4 -> 16-lane groups read 256B contiguous
        asm volatile("" ::: "memory");
#pragma unroll
        for (int rr = 0; rr < 4; ++rr) {
            const int row = rr * 4 + g0;
            v4f wv = __builtin_nontemporal_load(
                (const v4f*)(wb + (size_t)row * S + s4 * 64 + dq * 4));
            *(v4f*)&s_sub[wid][row][dq * 4] = wv;
        }
        asm volatile("s_waitcnt lgkmcnt(0)" ::: "memory");

        const float* vs = vw + (size_t)(s4 * 64) * D;
#pragma unroll 2
        for (int j = 0; j < 16; ++j) {
            float4 w0 = *(const float4*)&s_sub[wid][g0     ][j * 4];
            float4 w1 = *(const float4*)&s_sub[wid][g0 + 4 ][j * 4];
            float4 w2 = *(const float4*)&s_sub[wid][g0 + 8 ][j * 4];
            float4 w3 = *(const float4*)&s_sub[wid][g0 + 12][j * 4];
            const float* vp = vs + (size_t)(j * 4) * D + dq * 4;
            float4 v0 = *(const float4*)(vp);
            float4 v1 = *(const float4*)(vp + D);
            float4 v2 = *(const float4*)(vp + 2 * D);
            float4 v3 = *(const float4*)(vp + 3 * D);
            p0.x = fmaf(w0.w, v3.x, fmaf(w0.z, v2.x, fmaf(w0.y, v1.x, fmaf(w0.x, v0.x, p0.x))));
            p0.y = fmaf(w0.w, v3.y, fmaf(w0.z, v2.y, fmaf(w0.y, v1.y, fmaf(w0.x, v0.y, p0.y))));
            p0.z = fmaf(w0.w, v3.z, fmaf(w0.z, v2.z, fmaf(w0.y, v1.z, fmaf(w0.x, v0.z, p0.z))));
            p0.w = fmaf(w0.w, v3.w, fmaf(w0.z, v2.w, fmaf(w0.y, v1.w, fmaf(w0.x, v0.w, p0.w))));
            p1.x = fmaf(w1.w, v3.x, fmaf(w1.z, v2.x, fmaf(w1.y, v1.x, fmaf(w1.x, v0.x, p1.x))));
            p1.y = fmaf(w1.w, v3.y, fmaf(w1.z, v2.y, fmaf(w1.y, v1.y, fmaf(w1.x, v0.y, p1.y))));
            p1.z = fmaf(w1.w, v3.z, fmaf(w1.z, v2.z, fmaf(w1.y, v1.z, fmaf(w1.x, v0.z, p1.z))));
            p1.w = fmaf(w1.w, v3.w, fmaf(w1.z, v2.w, fmaf(w1.y, v1.w, fmaf(w1.x, v0.w, p1.w))));
            p2.x = fmaf(w2.w, v3.x, fmaf(w2.z, v2.x, fmaf(w2.y, v1.x, fmaf(w2.x, v0.x, p2.x))));
            p2.y = fmaf(w2.w, v3.y, fmaf(w2.z, v2.y, fmaf(w2.y, v1.y, fmaf(w2.x, v0.y, p2.y))));
            p2.z = fmaf(w2.w, v3.z, fmaf(w2.z, v2.z, fmaf(w2.y, v1.z, fmaf(w2.x, v0.z, p2.z))));
            p2.w = fmaf(w2.w, v3.w, fmaf(w2.z, v2.w, fmaf(w2.y, v1.w, fmaf(w2.x, v0.w, p2.w))));
            p3.x = fmaf(w3.w, v3.x, fmaf(w3.z, v2.x, fmaf(w3.y, v1.x, fmaf(w3.x, v0.x, p3.x))));
            p3.y = fmaf(w3.w, v3.y, fmaf(w3.z, v2.y, fmaf(w3.y, v1.y, fmaf(w3.x, v0.y, p3.y))));
            p3.z = fmaf(w3.w, v3.z, fmaf(w3.z, v2.z, fmaf(w3.y, v1.z, fmaf(w3.x, v0.z, p3.z))));
            p3.w = fmaf(w3.w, v3.w, fmaf(w3.z, v2.w, fmaf(w3.y, v1.w, fmaf(w3.x, v0.w, p3.w))));
        }
    }

    asm volatile("" ::: "memory");
    *(float4*)&s_sub[wid][g0     ][dq * 4] = p0;
    *(float4*)&s_sub[wid][g0 + 4 ][dq * 4] = p1;
    *(float4*)&s_sub[wid][g0 + 8 ][dq * 4] = p2;
    *(float4*)&s_sub[wid][g0 + 12][dq * 4] = p3;
    __syncthreads();
    {
        const int row = tid >> 4;
        const int dq2 = tid & 15;
        float4 a0 = *(const float4*)&s_sub[0][row][dq2 * 4];
        float4 a1 = *(const float4*)&s_sub[1][row][dq2 * 4];
        float4 a2 = *(const float4*)&s_sub[2][row][dq2 * 4];
        float4 a3 = *(const float4*)&s_sub[3][row][dq2 * 4];
        v4f o;
        o[0] = (a0.x + a1.x) + (a2.x + a3.x);
        o[1] = (a0.y + a1.y) + (a2.y + a3.y);
        o[2] = (a0.z + a1.z) + (a2.z + a3.z);
        o[3] = (a0.w + a1.w) + (a2.w + a3.w);
        __builtin_nontemporal_store(o, (v4f*)(oout + (size_t)row * D + dq2 * 4));
    }
}

extern "C" void kernel_launch(void* const* d_in, const int* in_sizes, int n_in,
                              void* d_out, int out_size, void* d_ws, size_t ws_size,
                              hipStream_t stream) {
    (void)in_sizes; (void)n_in; (void)out_size; (void)d_ws; (void)ws_size;
    const float* q     = (const float*)d_in[0];
    const float* k     = (const float*)d_in[1];
    const float* v     = (const float*)d_in[2];
    const float* prev  = (const float*)d_in[3];
    const float* mask  = (const float*)d_in[4];
    const float* scale = (const float*)d_in[5];

    float* out     = (float*)d_out;
    float* weights = out + (size_t)4 * 16 * 1024 * 64;
    float* scores  = weights + (size_t)4 * 16 * 1024 * 1024;

    attn_scores_kernel<<<dim3(4096), 256, 0, stream>>>(q, k, prev, mask, scale,
                                                       weights, scores);
    attn_pv_kernel<<<dim3(4096), 256, 0, stream>>>(weights, v, out);
}